// Round 8
// baseline (77.236 us; speedup 1.0000x reference)
//
#include <hip/hip_runtime.h>

#define N_   64
#define D_   128
#define L_   3136
#define K_   64
#define TL_  64
#define NG_  12     // pixel groups per image -> grid = 64*12 = 768 = 3 blocks/CU
// tiles per group: g==0 -> 5, else 4 (5 + 11*4 = 49 tiles of 64 pixels)
#define ASTR 68     // As row stride in floats (conflict-free f32 col writes)

typedef short  short8  __attribute__((ext_vector_type(8)));
typedef short  short4v __attribute__((ext_vector_type(4)));
typedef float  f32x16  __attribute__((ext_vector_type(16)));

static __device__ __forceinline__ unsigned short f2bf(float f) {
    unsigned u = __float_as_uint(f);                       // RNE f32 -> bf16 bits
    return (unsigned short)((u + 0x7FFFu + ((u >> 16) & 1u)) >> 16);
}

// Raw barrier: drains LDS (lgkmcnt) for write->barrier->read ordering, but
// does NOT drain vmcnt -- prefetch global loads stay in flight across it
// (the __syncthreads() vmcnt(0) drain is what killed r6's prefetch).
#define BARX() asm volatile("s_waitcnt lgkmcnt(0)\n\ts_barrier" ::: "memory")

// Full-MFMA fused NetVLAD main, software-pipelined:
//   tile top: consume v[] (sumsq + bf16 -> L1/L2/red_ss), issue next tile's
//   loads into v[], then 4 raw barriers carry the tile through
//   phase1(MFMA) -> softmax -> As -> phase2(MFMA). Loads complete under
//   compute; vmcnt waited only at next tile top (compiler-inserted).
__global__ __launch_bounds__(256, 3)
void vlad_main(const float* __restrict__ x, const float* __restrict__ w,
               float* __restrict__ vout, float* __restrict__ aout,
               int vstride, int astride)   // vstride==0 => atomic accumulate path
{
    __shared__ __align__(16) short L1[TL_ * D_];   // [l][dk] bf16, swz ^((l&15)<<4), 16KB
    __shared__ __align__(16) short L2[D_ * TL_];   // [dk][l] bf16, swz ^((dk&7)<<4), 16KB
    __shared__ __align__(16) float AsU[K_ * ASTR]; // f32 a*inv [k][p]; rows 0..15 double as red_ss; 17KB
    __shared__ float nrm_lds[TL_];
    __shared__ float dred[4][32];                  // softmax denominator exchange

    const int t    = threadIdx.x;
    const int lane = t & 63;
    const int wv   = __builtin_amdgcn_readfirstlane(t >> 6);  // 0..3
    const int n    = blockIdx.x / NG_;
    const int g    = blockIdx.x % NG_;
    const int tile0 = (g == 0) ? 0 : (4 * g + 1);
    const int ntile = (g == 0) ? 5 : 4;

    const int Mt = wv & 1;     // cluster-half (M) for both phases
    const int lg = lane >> 5;  // k-element group (0/1)
    const int lm = lane & 31;

    char* L1b = (char*)L1;
    char* L2b = (char*)L2;
    float (*red_ss)[ASTR] = (float (*)[ASTR])AsU;  // union: consumed before As written

    // ---- W fragments, loop-invariant, kept in 32 VGPRs ----
    short8 wf[8];
#pragma unroll
    for (int ks = 0; ks < 8; ++ks) {
        const float* wp = w + (size_t)(32 * Mt + lm) * D_ + 16 * ks + 8 * lg;
        const float4 wa = *(const float4*)wp;
        const float4 wb = *(const float4*)(wp + 4);
        short8 f;
        f[0]=f2bf(wa.x); f[1]=f2bf(wa.y); f[2]=f2bf(wa.z); f[3]=f2bf(wa.w);
        f[4]=f2bf(wb.x); f[5]=f2bf(wb.y); f[6]=f2bf(wb.z); f[7]=f2bf(wb.w);
        wf[ks] = f;
    }

    f32x16 acc0 = {0};   // V[k][d] C-frag, d-tile 2*(wv>>1)
    f32x16 acc1 = {0};   // d-tile 2*(wv>>1)+1
    float asum_acc = 0.f;

    const int q  = t >> 4;          // staging: d-rows 8q..8q+7
    const int l0 = (t & 15) * 4;    // staging: 4 pixels
    const float* xb = x + (size_t)n * D_ * L_;

    // ---- prologue: load tile 0 into registers ----
    float4 v[8];
    {
        const int p0 = tile0 * TL_;
#pragma unroll
        for (int r = 0; r < 8; ++r)
            v[r] = *(const float4*)(xb + (size_t)(8 * q + r) * L_ + p0 + l0);
    }

    for (int ti = 0; ti < ntile; ++ti) {
        // ---- stage current tile from v[]: sumsq + bf16 + L1 + L2 ----
#pragma unroll
        for (int j = 0; j < 4; ++j) {
            float s = 0.f;
#pragma unroll
            for (int r = 0; r < 8; ++r) {
                const float val = (&v[r].x)[j];
                s = fmaf(val, val, s);
            }
            red_ss[q][l0 + j] = s;
        }
        unsigned short sh[8][4];
#pragma unroll
        for (int r = 0; r < 8; ++r)
#pragma unroll
            for (int j = 0; j < 4; ++j) sh[r][j] = f2bf((&v[r].x)[j]);
#pragma unroll
        for (int j = 0; j < 4; ++j) {   // L1: per pixel, 8 consecutive dk (b128)
            const int l = l0 + j;
            short8 f;
#pragma unroll
            for (int r = 0; r < 8; ++r) f[r] = sh[r][j];
            *(short8*)(L1b + l * 256 + ((16 * q) ^ ((l & 15) << 4))) = f;
        }
#pragma unroll
        for (int r = 0; r < 8; ++r) {   // L2: per d, 4 consecutive l (b64)
            const int d = 8 * q + r;
            short4v f;
#pragma unroll
            for (int j = 0; j < 4; ++j) f[j] = sh[r][j];
            *(short4v*)(L2b + d * 128 + ((l0 * 2) ^ ((d & 7) << 4))) = f;
        }
        // ---- issue next tile's loads NOW (v[] just went dead); they stay
        //      in flight across the raw barriers below ----
        if (ti + 1 < ntile) {
            const int p0n = (tile0 + ti + 1) * TL_;
#pragma unroll
            for (int r = 0; r < 8; ++r)
                v[r] = *(const float4*)(xb + (size_t)(8 * q + r) * L_ + p0n + l0);
        }
        BARX();  // A: tile staged (red_ss/L1/L2 visible)
        // ---- per-pixel norm for asum (wave 0) ----
        if (t < TL_) {
            float ss = 0.f;
#pragma unroll
            for (int qq = 0; qq < 16; ++qq) ss += red_ss[qq][t];
            nrm_lds[t] = fmaxf(sqrtf(ss), 1e-12f);
        }
        // ---- phase 1: R = W * X (quadrant Mt x Nt), contraction dk=128 ----
        f32x16 r1 = {0};
        {
            const int l = 32 * (wv >> 1) + lm;   // pixel = col = lane&31
            const int rowoff = l * 256;
            const int swz = (l & 15) << 4;
            __builtin_amdgcn_s_setprio(1);
#pragma unroll
            for (int ks = 0; ks < 8; ++ks) {
                const short8 bfr = *(short8*)(L1b + rowoff + (((16 * ks + 8 * lg) * 2) ^ swz));
                r1 = __builtin_amdgcn_mfma_f32_32x32x16_bf16(wf[ks], bfr, r1, 0, 0, 0);
            }
            __builtin_amdgcn_s_setprio(0);
        }
        // ---- per-thread inv from red_ss (replaces r7's bar2) ----
        const int myl = 32 * (wv >> 1) + lm;
        float ss16 = 0.f;
#pragma unroll
        for (int qq = 0; qq < 16; ++qq) ss16 += red_ss[qq][myl];
        const float invp = 1.f / fmaxf(sqrtf(ss16), 1e-12f);
        // ---- softmax over k (no max-sub; |logit*inv| <= ||w_k|| ~ 0.6) ----
        float e[16];
        float s = 0.f;
#pragma unroll
        for (int r = 0; r < 16; ++r) { e[r] = __expf(r1[r] * invp); s += e[r]; }
        s += __shfl_xor(s, 32);              // combine the two k-halves per pixel
        if (lane < 32) dred[wv][lm] = s;
        BARX();  // B: dred ready (and red_ss fully consumed)
        const float denom = dred[wv][lm] + dred[wv ^ 1][lm];   // cross-Mt partner
        const float sc = invp / denom;       // A_s = a * inv (agg uses raw X)
#pragma unroll
        for (int r = 0; r < 16; ++r) {       // f32 store: 1 dword/lane, conflict-free
            const int k = 32 * Mt + (r & 3) + 8 * (r >> 2) + 4 * lg;
            AsU[k * ASTR + 32 * (wv >> 1) + lm] = e[r] * sc;
        }
        BARX();  // C: A_s ready
        // ---- phase 2: V += A_s * X^T, contraction l=64 ----
        {
            short8 af[4];
            const float* arow = AsU + (32 * Mt + lm) * ASTR;
#pragma unroll
            for (int ks = 0; ks < 4; ++ks) {
                const float* ap = arow + 16 * ks + 8 * lg;
                const float4 a0 = *(const float4*)ap;
                const float4 a1 = *(const float4*)(ap + 4);
                short8 f;
                f[0]=f2bf(a0.x); f[1]=f2bf(a0.y); f[2]=f2bf(a0.z); f[3]=f2bf(a0.w);
                f[4]=f2bf(a1.x); f[5]=f2bf(a1.y); f[6]=f2bf(a1.z); f[7]=f2bf(a1.w);
                af[ks] = f;
            }
            __builtin_amdgcn_s_setprio(1);
#pragma unroll
            for (int nt = 0; nt < 2; ++nt) {
                const int dk = 32 * (2 * (wv >> 1) + nt) + lm;  // d = col = lane&31
                const int rowoff = dk * 128;
                const int swz = (dk & 7) << 4;
                f32x16 a = (nt == 0) ? acc0 : acc1;
#pragma unroll
                for (int ks = 0; ks < 4; ++ks) {
                    const short8 bfr = *(short8*)(L2b + rowoff + (((16 * ks + 8 * lg) * 2) ^ swz));
                    a = __builtin_amdgcn_mfma_f32_32x32x16_bf16(af[ks], bfr, a, 0, 0, 0);
                }
                if (nt == 0) acc0 = a; else acc1 = a;
            }
            __builtin_amdgcn_s_setprio(0);
        }
        // ---- asum partial: asum[k] += sum_l A_s[k][l]*nrm[l] ----
        {
            const int k  = 16 * wv + (lane & 15);
            const int c4 = lane >> 4;                 // l-chunk 16*c4
            const float* ap = AsU + k * ASTR + 16 * c4;
            float ps = 0.f;
#pragma unroll
            for (int i = 0; i < 16; ++i)
                ps = fmaf(ap[i], nrm_lds[16 * c4 + i], ps);
            ps += __shfl_xor(ps, 16);
            ps += __shfl_xor(ps, 32);
            asum_acc += ps;
        }
        BARX();  // D: L1/L2/AsU/nrm consumers done (WAR for next staging)
    }
    // ---- commit: per-group slab (plain stores) or atomic fallback ----
    {
        const int dbase0 = 32 * (2 * (wv >> 1));
        float* vb = vstride ? (vout + (size_t)g * vstride) : vout;
#pragma unroll
        for (int r = 0; r < 16; ++r) {
            const int k = 32 * Mt + (r & 3) + 8 * (r >> 2) + 4 * lg;
            float* row = vb + ((size_t)n * K_ + k) * D_ + lm;
            if (vstride) {
                row[dbase0]      = acc0[r];
                row[dbase0 + 32] = acc1[r];
            } else {
                atomicAdd(&row[dbase0],      acc0[r]);
                atomicAdd(&row[dbase0 + 32], acc1[r]);
            }
        }
        if (lane < 16) {
            const int k = 16 * wv + lane;
            if (astride) aout[(size_t)g * astride + n * K_ + k] = asum_acc;
            else atomicAdd(&aout[n * K_ + k], asum_acc);
        }
    }
}

// Finalize, spread: one block per (n, k-octet). Sum slabs, subtract a*c,
// intra-normalize over d. Global norm: intra-normalized rows are unit-norm,
// so ||vlad_flat|| = sqrt(K) = 8 exactly (rows here are far above the 1e-12
// eps clamp) -> scale by 1/8. No cross-block reduction needed.
__global__ __launch_bounds__(256)
void vlad_fin(const float* __restrict__ vacc, const float* __restrict__ asum,
              const float* __restrict__ cent, float* __restrict__ out, int npart)
{
    const int t   = threadIdx.x;
    const int b   = blockIdx.x;
    const int n   = b >> 3;
    const int oct = b & 7;
    const int k   = oct * 8 + (t >> 5);   // 8 k-rows per block
    const int c   = t & 31;               // float4 column; d = 4c

    float a = 0.f;
#pragma unroll 4
    for (int g = 0; g < npart; ++g) a += asum[(size_t)g * (N_ * K_) + n * K_ + k];

    const size_t off4 = ((size_t)(n * K_ + k) * D_ >> 2) + c;
    float4 v = make_float4(0.f, 0.f, 0.f, 0.f);
#pragma unroll 4
    for (int g = 0; g < npart; ++g) {
        const float4 s = ((const float4*)vacc)[(size_t)g * ((size_t)N_ * K_ * D_ >> 2) + off4];
        v.x += s.x; v.y += s.y; v.z += s.z; v.w += s.w;
    }
    const float4 cc = ((const float4*)cent)[((size_t)k * D_ >> 2) + c];
    v.x -= a * cc.x; v.y -= a * cc.y; v.z -= a * cc.z; v.w -= a * cc.w;
    float ss = v.x * v.x + v.y * v.y + v.z * v.z + v.w * v.w;
    ss += __shfl_xor(ss, 1);
    ss += __shfl_xor(ss, 2);
    ss += __shfl_xor(ss, 4);
    ss += __shfl_xor(ss, 8);
    ss += __shfl_xor(ss, 16);             // stays within the 32-lane row group
    const float s1 = 0.125f / fmaxf(sqrtf(ss), 1e-12f);   // intra-norm * 1/sqrt(K)
    float4 o;
    o.x = v.x * s1; o.y = v.y * s1; o.z = v.z * s1; o.w = v.w * s1;
    ((float4*)out)[off4] = o;
}

extern "C" void kernel_launch(void* const* d_in, const int* in_sizes, int n_in,
                              void* d_out, int out_size, void* d_ws, size_t ws_size,
                              hipStream_t stream)
{
    const float* x = (const float*)d_in[0];   // [N, D, H, W]
    const float* w = (const float*)d_in[1];   // [K, D]
    const float* c = (const float*)d_in[2];   // [K, D]
    float* out = (float*)d_out;               // [N, K*D]

    const size_t vs  = (size_t)N_ * K_ * D_;  // 524288
    const size_t as_ = (size_t)N_ * K_;       // 4096
    const size_t need = (NG_ * vs + NG_ * as_) * sizeof(float);  // ~25.4 MB
    float* vacc = (float*)d_ws;

    if (ws_size >= need) {
        float* ap = vacc + NG_ * vs;
        vlad_main<<<dim3(N_ * NG_), dim3(256), 0, stream>>>(x, w, vacc, ap,
                                                            (int)vs, (int)as_);
        vlad_fin<<<dim3(N_ * 8), dim3(256), 0, stream>>>(vacc, ap, c, out, NG_);
    } else {
        float* ap = vacc + vs;
        hipMemsetAsync(d_ws, 0, (vs + as_) * sizeof(float), stream);
        vlad_main<<<dim3(N_ * NG_), dim3(256), 0, stream>>>(x, w, vacc, ap, 0, 0);
        vlad_fin<<<dim3(N_ * 8), dim3(256), 0, stream>>>(vacc, ap, c, out, 1);
    }
}

// Round 9
// 37.874 us; speedup vs baseline: 2.0393x; 2.0393x over previous
//
#include <hip/hip_runtime.h>

#define N_   64
#define D_   128
#define L_   3136
#define K_   64
#define TL_  64
#define NG_  8      // pixel groups per image -> grid = 64*8 = 512 = 2 blocks/CU
// tiles per group: g==0 -> 7, else 6 (7 + 7*6 = 49 tiles of 64 pixels)
#define ASH  72     // As row stride in shorts (144B: 16B-aligned rows)

typedef short  short8  __attribute__((ext_vector_type(8)));
typedef short  short4v __attribute__((ext_vector_type(4)));
typedef float  f32x16  __attribute__((ext_vector_type(16)));

static __device__ __forceinline__ unsigned short f2bf(float f) {
    unsigned u = __float_as_uint(f);                       // RNE f32 -> bf16 bits
    return (unsigned short)((u + 0x7FFFu + ((u >> 16) & 1u)) >> 16);
}
static __device__ __forceinline__ float bf2f(short s) {
    return __uint_as_float(((unsigned)(unsigned short)s) << 16);
}

// Raw barrier: drains LDS (lgkmcnt) for write->barrier->read ordering, but
// does NOT drain vmcnt -- prefetch global loads stay in flight across it.
#define BARX() asm volatile("s_waitcnt lgkmcnt(0)\n\ts_barrier" ::: "memory")

// Full-MFMA fused NetVLAD main, software-pipelined.
// r6/r8 lesson: launch_bounds(256,3) caps combined VGPR+AGPR at 128 (HW
// granule 64); baseline uses ~116, so the 32-reg prefetch spilled to scratch
// both times. (256,2) raises the cap to 256: prefetch stays in registers,
// occupancy 2 blocks/CU (8 waves). As is bf16 now: phase2 reads fragments
// directly (no f32->bf16 repack), LDS ~42KB.
__global__ __launch_bounds__(256, 2)
void vlad_main(const float* __restrict__ x, const float* __restrict__ w,
               float* __restrict__ vout, float* __restrict__ aout,
               int vstride, int astride)   // vstride==0 => atomic accumulate path
{
    __shared__ __align__(16) short L1[TL_ * D_];   // [l][dk] bf16, swz ^((l&15)<<4), 16KB
    __shared__ __align__(16) short L2[D_ * TL_];   // [dk][l] bf16, swz ^((dk&7)<<4), 16KB
    __shared__ __align__(16) char  AsRaw[K_ * ASH * 2];  // bf16 a*inv [k][p], 9.2KB;
                                                         // rows 0..15 double as f32 red_ss[16][68]
    __shared__ float nrm_lds[TL_];
    __shared__ float dred[4][32];                  // softmax denominator exchange

    const int t    = threadIdx.x;
    const int lane = t & 63;
    const int wv   = __builtin_amdgcn_readfirstlane(t >> 6);  // 0..3
    const int n    = blockIdx.x / NG_;
    const int g    = blockIdx.x % NG_;
    const int tile0 = (g == 0) ? 0 : (7 + 6 * (g - 1));
    const int ntile = (g == 0) ? 7 : 6;

    const int Mt = wv & 1;     // cluster-half (M) for both phases
    const int lg = lane >> 5;  // k-element group (0/1)
    const int lm = lane & 31;

    char* L1b = (char*)L1;
    char* L2b = (char*)L2;
    short* AsS = (short*)AsRaw;
    float (*red_ss)[68] = (float (*)[68])AsRaw;    // union: consumed before As written

    // ---- W fragments, loop-invariant, kept in 32 VGPRs ----
    short8 wf[8];
#pragma unroll
    for (int ks = 0; ks < 8; ++ks) {
        const float* wp = w + (size_t)(32 * Mt + lm) * D_ + 16 * ks + 8 * lg;
        const float4 wa = *(const float4*)wp;
        const float4 wb = *(const float4*)(wp + 4);
        short8 f;
        f[0]=f2bf(wa.x); f[1]=f2bf(wa.y); f[2]=f2bf(wa.z); f[3]=f2bf(wa.w);
        f[4]=f2bf(wb.x); f[5]=f2bf(wb.y); f[6]=f2bf(wb.z); f[7]=f2bf(wb.w);
        wf[ks] = f;
    }

    f32x16 acc0 = {0};   // V[k][d] C-frag, d-tile 2*(wv>>1)
    f32x16 acc1 = {0};   // d-tile 2*(wv>>1)+1
    float asum_acc = 0.f;

    const int q  = t >> 4;          // staging: d-rows 8q..8q+7
    const int l0 = (t & 15) * 4;    // staging: 4 pixels
    const float* xb = x + (size_t)n * D_ * L_;

    // ---- prologue: load tile 0 into registers ----
    float4 v[8];
    {
        const int p0 = tile0 * TL_;
#pragma unroll
        for (int r = 0; r < 8; ++r)
            v[r] = *(const float4*)(xb + (size_t)(8 * q + r) * L_ + p0 + l0);
    }

    for (int ti = 0; ti < ntile; ++ti) {
        // ---- stage current tile from v[]: sumsq + bf16 + L1 + L2 ----
#pragma unroll
        for (int j = 0; j < 4; ++j) {
            float s = 0.f;
#pragma unroll
            for (int r = 0; r < 8; ++r) {
                const float val = (&v[r].x)[j];
                s = fmaf(val, val, s);
            }
            red_ss[q][l0 + j] = s;
        }
        unsigned short sh[8][4];
#pragma unroll
        for (int r = 0; r < 8; ++r)
#pragma unroll
            for (int j = 0; j < 4; ++j) sh[r][j] = f2bf((&v[r].x)[j]);
#pragma unroll
        for (int j = 0; j < 4; ++j) {   // L1: per pixel, 8 consecutive dk (b128)
            const int l = l0 + j;
            short8 f;
#pragma unroll
            for (int r = 0; r < 8; ++r) f[r] = sh[r][j];
            *(short8*)(L1b + l * 256 + ((16 * q) ^ ((l & 15) << 4))) = f;
        }
#pragma unroll
        for (int r = 0; r < 8; ++r) {   // L2: per d, 4 consecutive l (b64)
            const int d = 8 * q + r;
            short4v f;
#pragma unroll
            for (int j = 0; j < 4; ++j) f[j] = sh[r][j];
            *(short4v*)(L2b + d * 128 + ((l0 * 2) ^ ((d & 7) << 4))) = f;
        }
        // ---- issue next tile's loads NOW (v[] just went dead); they stay
        //      in flight across the raw barriers below ----
        if (ti + 1 < ntile) {
            const int p0n = (tile0 + ti + 1) * TL_;
#pragma unroll
            for (int r = 0; r < 8; ++r)
                v[r] = *(const float4*)(xb + (size_t)(8 * q + r) * L_ + p0n + l0);
        }
        BARX();  // A: tile staged (red_ss/L1/L2 visible)
        // ---- per-pixel norm for asum (wave 0) ----
        if (t < TL_) {
            float ss = 0.f;
#pragma unroll
            for (int qq = 0; qq < 16; ++qq) ss += red_ss[qq][t];
            nrm_lds[t] = fmaxf(sqrtf(ss), 1e-12f);
        }
        // ---- phase 1: R = W * X (quadrant Mt x Nt), contraction dk=128 ----
        f32x16 r1 = {0};
        {
            const int l = 32 * (wv >> 1) + lm;   // pixel = col = lane&31
            const int rowoff = l * 256;
            const int swz = (l & 15) << 4;
            __builtin_amdgcn_s_setprio(1);
#pragma unroll
            for (int ks = 0; ks < 8; ++ks) {
                const short8 bfr = *(short8*)(L1b + rowoff + (((16 * ks + 8 * lg) * 2) ^ swz));
                r1 = __builtin_amdgcn_mfma_f32_32x32x16_bf16(wf[ks], bfr, r1, 0, 0, 0);
            }
            __builtin_amdgcn_s_setprio(0);
        }
        // ---- per-thread inv from red_ss ----
        const int myl = 32 * (wv >> 1) + lm;
        float ss16 = 0.f;
#pragma unroll
        for (int qq = 0; qq < 16; ++qq) ss16 += red_ss[qq][myl];
        const float invp = 1.f / fmaxf(sqrtf(ss16), 1e-12f);
        // ---- softmax over k (no max-sub; |logit*inv| <= ||w_k|| ~ 0.6) ----
        float e[16];
        float s = 0.f;
#pragma unroll
        for (int r = 0; r < 16; ++r) { e[r] = __expf(r1[r] * invp); s += e[r]; }
        s += __shfl_xor(s, 32);              // combine the two k-halves per pixel
        if (lane < 32) dred[wv][lm] = s;
        BARX();  // B: dred ready (and red_ss fully consumed)
        const float denom = dred[wv][lm] + dred[wv ^ 1][lm];   // cross-Mt partner
        const float sc = invp / denom;       // A_s = a * inv (agg uses raw X)
        {
            const int colp = 32 * (wv >> 1) + lm;
#pragma unroll
            for (int r = 0; r < 16; ++r) {   // bf16 store: 2B/lane, 2-way alias (free)
                const int k = 32 * Mt + (r & 3) + 8 * (r >> 2) + 4 * lg;
                AsS[k * ASH + colp] = (short)f2bf(e[r] * sc);
            }
        }
        BARX();  // C: A_s ready
        // ---- phase 2: V += A_s * X^T, contraction l=64 (af read direct) ----
        {
            short8 af[4];
            const char* arow = AsRaw + (size_t)(32 * Mt + lm) * (ASH * 2);
#pragma unroll
            for (int ks = 0; ks < 4; ++ks)
                af[ks] = *(const short8*)(arow + (16 * ks + 8 * lg) * 2);
            __builtin_amdgcn_s_setprio(1);
#pragma unroll
            for (int nt = 0; nt < 2; ++nt) {
                const int dk = 32 * (2 * (wv >> 1) + nt) + lm;  // d = col = lane&31
                const int rowoff = dk * 128;
                const int swz = (dk & 7) << 4;
                f32x16 a = (nt == 0) ? acc0 : acc1;
#pragma unroll
                for (int ks = 0; ks < 4; ++ks) {
                    const short8 bfr = *(short8*)(L2b + rowoff + (((16 * ks + 8 * lg) * 2) ^ swz));
                    a = __builtin_amdgcn_mfma_f32_32x32x16_bf16(af[ks], bfr, a, 0, 0, 0);
                }
                if (nt == 0) acc0 = a; else acc1 = a;
            }
            __builtin_amdgcn_s_setprio(0);
        }
        // ---- asum partial: asum[k] += sum_l A_s[k][l]*nrm[l] (bf16 reads) ----
        {
            const int k  = 16 * wv + (lane & 15);
            const int c4 = lane >> 4;                 // l-chunk 16*c4
            const char* ap = AsRaw + (size_t)k * (ASH * 2) + c4 * 32;
            const short8 a0 = *(const short8*)ap;
            const short8 a1 = *(const short8*)(ap + 16);
            float ps = 0.f;
#pragma unroll
            for (int i = 0; i < 8; ++i) {
                ps = fmaf(bf2f(a0[i]), nrm_lds[16 * c4 + i],     ps);
                ps = fmaf(bf2f(a1[i]), nrm_lds[16 * c4 + 8 + i], ps);
            }
            ps += __shfl_xor(ps, 16);
            ps += __shfl_xor(ps, 32);
            asum_acc += ps;
        }
        BARX();  // D: L1/L2/As/nrm consumers done (WAR for next staging)
    }
    // ---- commit: per-group slab (plain stores) or atomic fallback ----
    {
        const int dbase0 = 32 * (2 * (wv >> 1));
        float* vb = vstride ? (vout + (size_t)g * vstride) : vout;
#pragma unroll
        for (int r = 0; r < 16; ++r) {
            const int k = 32 * Mt + (r & 3) + 8 * (r >> 2) + 4 * lg;
            float* row = vb + ((size_t)n * K_ + k) * D_ + lm;
            if (vstride) {
                row[dbase0]      = acc0[r];
                row[dbase0 + 32] = acc1[r];
            } else {
                atomicAdd(&row[dbase0],      acc0[r]);
                atomicAdd(&row[dbase0 + 32], acc1[r]);
            }
        }
        if (lane < 16) {
            const int k = 16 * wv + lane;
            if (astride) aout[(size_t)g * astride + n * K_ + k] = asum_acc;
            else atomicAdd(&aout[n * K_ + k], asum_acc);
        }
    }
}

// Finalize, spread: one block per (n, k-octet). Sum slabs, subtract a*c,
// intra-normalize over d. Global norm = sqrt(K) = 8 exactly (unit rows).
__global__ __launch_bounds__(256)
void vlad_fin(const float* __restrict__ vacc, const float* __restrict__ asum,
              const float* __restrict__ cent, float* __restrict__ out, int npart)
{
    const int t   = threadIdx.x;
    const int b   = blockIdx.x;
    const int n   = b >> 3;
    const int oct = b & 7;
    const int k   = oct * 8 + (t >> 5);   // 8 k-rows per block
    const int c   = t & 31;               // float4 column; d = 4c

    float a = 0.f;
#pragma unroll 4
    for (int g = 0; g < npart; ++g) a += asum[(size_t)g * (N_ * K_) + n * K_ + k];

    const size_t off4 = ((size_t)(n * K_ + k) * D_ >> 2) + c;
    float4 v = make_float4(0.f, 0.f, 0.f, 0.f);
#pragma unroll 4
    for (int g = 0; g < npart; ++g) {
        const float4 s = ((const float4*)vacc)[(size_t)g * ((size_t)N_ * K_ * D_ >> 2) + off4];
        v.x += s.x; v.y += s.y; v.z += s.z; v.w += s.w;
    }
    const float4 cc = ((const float4*)cent)[((size_t)k * D_ >> 2) + c];
    v.x -= a * cc.x; v.y -= a * cc.y; v.z -= a * cc.z; v.w -= a * cc.w;
    float ss = v.x * v.x + v.y * v.y + v.z * v.z + v.w * v.w;
    ss += __shfl_xor(ss, 1);
    ss += __shfl_xor(ss, 2);
    ss += __shfl_xor(ss, 4);
    ss += __shfl_xor(ss, 8);
    ss += __shfl_xor(ss, 16);             // stays within the 32-lane row group
    const float s1 = 0.125f / fmaxf(sqrtf(ss), 1e-12f);   // intra-norm * 1/sqrt(K)
    float4 o;
    o.x = v.x * s1; o.y = v.y * s1; o.z = v.z * s1; o.w = v.w * s1;
    ((float4*)out)[off4] = o;
}

extern "C" void kernel_launch(void* const* d_in, const int* in_sizes, int n_in,
                              void* d_out, int out_size, void* d_ws, size_t ws_size,
                              hipStream_t stream)
{
    const float* x = (const float*)d_in[0];   // [N, D, H, W]
    const float* w = (const float*)d_in[1];   // [K, D]
    const float* c = (const float*)d_in[2];   // [K, D]
    float* out = (float*)d_out;               // [N, K*D]

    const size_t vs  = (size_t)N_ * K_ * D_;  // 524288
    const size_t as_ = (size_t)N_ * K_;       // 4096
    const size_t need = (NG_ * vs + NG_ * as_) * sizeof(float);  // ~16.9 MB
    float* vacc = (float*)d_ws;

    if (ws_size >= need) {
        float* ap = vacc + NG_ * vs;
        vlad_main<<<dim3(N_ * NG_), dim3(256), 0, stream>>>(x, w, vacc, ap,
                                                            (int)vs, (int)as_);
        vlad_fin<<<dim3(N_ * 8), dim3(256), 0, stream>>>(vacc, ap, c, out, NG_);
    } else {
        float* ap = vacc + vs;
        hipMemsetAsync(d_ws, 0, (vs + as_) * sizeof(float), stream);
        vlad_main<<<dim3(N_ * NG_), dim3(256), 0, stream>>>(x, w, vacc, ap, 0, 0);
        vlad_fin<<<dim3(N_ * 8), dim3(256), 0, stream>>>(vacc, ap, c, out, 1);
    }
}